// Round 1
// baseline (210.121 us; speedup 1.0000x reference)
//
#include <hip/hip_runtime.h>
#include <cstdint>
#include <cstddef>

using f16   = _Float16;
using half8 = __attribute__((ext_vector_type(8))) _Float16;
using f32x4 = __attribute__((ext_vector_type(4))) float;

#define DINL __device__ __forceinline__

// CK-style cast pattern: generic ptr -> uintptr_t -> addrspace-qualified ptr.
DINL void gload_lds16(const void* gptr, void* lptr) {
  __builtin_amdgcn_global_load_lds(
      reinterpret_cast<const __attribute__((address_space(1))) uint32_t*>(
          reinterpret_cast<uintptr_t>(gptr)),
      reinterpret_cast<__attribute__((address_space(3))) uint32_t*>(
          reinterpret_cast<uintptr_t>(lptr)),
      16, 0, 0);
}

DINL float fast_silu(float x) { return x / (1.0f + __expf(-x)); }

// ---------------------------------------------------------------------------
// Basis kernel: per (token, dim) element x -> 8 fp16 channels:
//   [B0..B5 (cubic B-spline basis on uniform knots t_j=(j-3)*2/3-1), silu(x), 0]
// Uniform-knot closed form: for x in interval m (t_m <= x < t_{m+1}),
// u=(x-t_m)/h, nonzero basis are channels m-3..m with the standard uniform
// cubic pieces; identical (C^2-continuous) to the reference Cox-de Boor.
// ---------------------------------------------------------------------------
__global__ __launch_bounds__(256)
void basis_kernel(const float* __restrict__ X, f16* __restrict__ A, int total) {
  int idx = blockIdx.x * 256 + threadIdx.x;
  if (idx >= total) return;
  float x  = X[idx];
  float xs = (x + 3.0f) * 1.5f;        // (x - t0)/h, t0=-3, h=2/3
  float mf = floorf(xs);
  int   m  = (int)mf;
  float p0 = 0.f, p1 = 0.f, p2 = 0.f, p3 = 0.f;
  if (m >= 0 && m <= 8) {              // inside [-3, 3)
    float u  = xs - mf;
    float u2 = u * u, u3 = u2 * u;
    float um = 1.0f - u;
    p3 = u3 * (1.0f / 6.0f);                                   // channel m
    p2 = (1.0f + 3.0f * u + 3.0f * u2 - 3.0f * u3) * (1.0f / 6.0f); // m-1
    p1 = (4.0f - 6.0f * u2 + 3.0f * u3) * (1.0f / 6.0f);       // m-2
    p0 = um * um * um * (1.0f / 6.0f);                         // m-3
  }
  half8 o;
#pragma unroll
  for (int j = 0; j < 6; ++j) {
    int dmj = m - j;
    float v = (dmj == 0) ? p3 : (dmj == 1) ? p2 : (dmj == 2) ? p1
            : (dmj == 3) ? p0 : 0.0f;
    o[j] = (f16)v;
  }
  o[6] = (f16)fast_silu(x);
  o[7] = (f16)0.0f;
  *reinterpret_cast<half8*>(A + (size_t)idx * 8) = o;
}

// ---------------------------------------------------------------------------
// Weight prep: Wt[o][d*8+b] = coef[d][o][b]*scale_sp[d][o] (b<6),
//              ch6 = scale_base[d][o], ch7 = 0.   (fp16, row-major [O][K])
// ---------------------------------------------------------------------------
__global__ __launch_bounds__(256)
void prep_w_kernel(const float* __restrict__ coef, const float* __restrict__ ssp,
                   const float* __restrict__ sb, f16* __restrict__ Wt,
                   int Din, int Dout) {
  int idx = blockIdx.x * 256 + threadIdx.x;
  if (idx >= Din * Dout) return;
  int o = idx / Din;
  int d = idx - o * Din;
  float s = ssp[(size_t)d * Dout + o];
  const float* c = coef + ((size_t)d * Dout + o) * 6;
  half8 wv;
#pragma unroll
  for (int b = 0; b < 6; ++b) wv[b] = (f16)(c[b] * s);
  wv[6] = (f16)sb[(size_t)d * Dout + o];
  wv[7] = (f16)0.0f;
  *reinterpret_cast<half8*>(Wt + (size_t)idx * 8) = wv;
}

// ---------------------------------------------------------------------------
// fp16 MFMA GEMM: C[M,N] = A[M,K] * Bt[N,K]^T, epilogue C = ns[col]*acc+nb[col]
// m97-style: BMx128 tile, BK=64, global_load_lds(16B), 4 waves, 2 barriers/K.
// BM=128: waves 2x2 (64x64 each).  BM=64: waves 1x4 (64x32 each).
// Fragment layout (verified gfx950 convention): lane holds 8 contiguous K
// elems at row (lane&15), k-block (lane>>4); D: col=lane&15, row=(lane>>4)*4+r.
// ---------------------------------------------------------------------------
template <int BM>
__global__ __launch_bounds__(256)
void gemm_f16(const f16* __restrict__ A, const f16* __restrict__ Bt,
              float* __restrict__ C, const float* __restrict__ nscale,
              const float* __restrict__ nbias, int N, int K) {
  constexpr int NWM   = BM / 64;       // wave rows groups: 2 or 1
  constexpr int NWN   = 4 / NWM;       // wave col groups: 2 or 4
  constexpr int WCOLS = 128 / NWN;     // 64 or 32 cols per wave
  constexpr int NJ    = WCOLS / 16;    // 4 or 2 col fragments
  constexpr int QA    = BM / 32;       // A staging issues

  __shared__ alignas(16) f16 lsA[BM * 64];
  __shared__ alignas(16) f16 lsB[128 * 64];

  const int tid  = threadIdx.x;
  const int w    = tid >> 6;
  const int lane = tid & 63;
  const int m0   = blockIdx.y * BM;
  const int n0   = blockIdx.x * 128;
  const int wm   = w / NWN;
  const int wn   = w % NWN;

  f32x4 acc[4][NJ] = {};

  const int lr = lane >> 3;            // row within 8-row chunk
  const int lc = (lane & 7) * 8;       // k-elem offset within 64
  const f16* Ab = A  + (size_t)(m0 + w * 8 + lr) * K + lc;
  const f16* Bb = Bt + (size_t)(n0 + w * 8 + lr) * K + lc;

  for (int k0 = 0; k0 < K; k0 += 64) {
#pragma unroll
    for (int q = 0; q < QA; ++q)
      gload_lds16(Ab + (size_t)q * 32 * K + k0, &lsA[(q * 32 + w * 8) * 64]);
#pragma unroll
    for (int q = 0; q < 4; ++q)
      gload_lds16(Bb + (size_t)q * 32 * K + k0, &lsB[(q * 32 + w * 8) * 64]);
    __syncthreads();

#pragma unroll
    for (int kk = 0; kk < 2; ++kk) {
      half8 av[4], bv[NJ];
#pragma unroll
      for (int i = 0; i < 4; ++i)
        av[i] = *reinterpret_cast<const half8*>(
            &lsA[(wm * 64 + i * 16 + (lane & 15)) * 64 + kk * 32 + (lane >> 4) * 8]);
#pragma unroll
      for (int j = 0; j < NJ; ++j)
        bv[j] = *reinterpret_cast<const half8*>(
            &lsB[(wn * WCOLS + j * 16 + (lane & 15)) * 64 + kk * 32 + (lane >> 4) * 8]);
#pragma unroll
      for (int i = 0; i < 4; ++i)
#pragma unroll
        for (int j = 0; j < NJ; ++j)
          acc[i][j] = __builtin_amdgcn_mfma_f32_16x16x32_f16(av[i], bv[j], acc[i][j], 0, 0, 0);
    }
    __syncthreads();
  }

#pragma unroll
  for (int j = 0; j < NJ; ++j) {
    int col  = n0 + wn * WCOLS + j * 16 + (lane & 15);
    float ns = nscale[col], nb = nbias[col];
#pragma unroll
    for (int i = 0; i < 4; ++i) {
      int rowb = m0 + wm * 64 + i * 16 + (lane >> 4) * 4;
#pragma unroll
      for (int r = 0; r < 4; ++r)
        C[(size_t)(rowb + r) * N + col] = ns * acc[i][j][r] + nb;
    }
  }
}

// ---------------------------------------------------------------------------
// Residual add + LayerNorm(256) + exact GELU, one wave per row, in place.
// ---------------------------------------------------------------------------
__global__ __launch_bounds__(256)
void ln_gelu_kernel(const float* __restrict__ T2, const float* __restrict__ X,
                    const float* __restrict__ gamma, const float* __restrict__ beta,
                    float* __restrict__ out, int rows) {
  int row  = blockIdx.x * 4 + (threadIdx.x >> 6);
  int lane = threadIdx.x & 63;
  if (row >= rows) return;
  const float* t2 = T2 + (size_t)row * 256;
  const float* xr = X  + (size_t)row * 256;
  float h[4];
  float s = 0.f;
#pragma unroll
  for (int j = 0; j < 4; ++j) {
    int c = j * 64 + lane;
    h[j]  = t2[c] + xr[c];
    s    += h[j];
  }
#pragma unroll
  for (int o = 32; o >= 1; o >>= 1) s += __shfl_xor(s, o);
  float mu = s * (1.0f / 256.0f);
  float vs = 0.f;
#pragma unroll
  for (int j = 0; j < 4; ++j) { float d = h[j] - mu; vs += d * d; }
#pragma unroll
  for (int o = 32; o >= 1; o >>= 1) vs += __shfl_xor(vs, o);
  float inv = rsqrtf(vs * (1.0f / 256.0f) + 1e-5f);
  float* orow = out + (size_t)row * 256;
#pragma unroll
  for (int j = 0; j < 4; ++j) {
    int c   = j * 64 + lane;
    float v = (h[j] - mu) * inv * gamma[c] + beta[c];
    orow[c] = 0.5f * v * (1.0f + erff(v * 0.70710678118654752f));
  }
}

// ---------------------------------------------------------------------------
extern "C" void kernel_launch(void* const* d_in, const int* in_sizes, int n_in,
                              void* d_out, int out_size, void* d_ws, size_t ws_size,
                              hipStream_t stream) {
  (void)in_sizes; (void)n_in; (void)out_size; (void)ws_size;
  const float* x     = (const float*)d_in[0];
  // d_in[1] = grid1 (uniform knots, folded into closed-form basis)
  const float* coef1 = (const float*)d_in[2];
  const float* sb1   = (const float*)d_in[3];
  const float* ssp1  = (const float*)d_in[4];
  const float* ns1   = (const float*)d_in[5];
  const float* nb1   = (const float*)d_in[6];
  // d_in[7] = grid2
  const float* coef2 = (const float*)d_in[8];
  const float* sb2   = (const float*)d_in[9];
  const float* ssp2  = (const float*)d_in[10];
  const float* ns2   = (const float*)d_in[11];
  const float* nb2   = (const float*)d_in[12];
  const float* lgam  = (const float*)d_in[13];
  const float* lbet  = (const float*)d_in[14];
  float* out = (float*)d_out;

  const int Ntok = 16 * 1024;  // B*S
  const int D0 = 256, D1 = 512, D2 = 256;
  const int K1 = D0 * 8;       // 2048
  const int K2 = D1 * 8;       // 4096

  // Workspace layout (~172 MB):
  //   [0, 134MB)        : A region (A1 [Ntok,K1] fp16, later reused as A2 [Ntok,K2])
  //   [134, 167.5MB)    : h1 [Ntok, D1] fp32
  //   then Wt1 (2MB), Wt2 (2MB)
  char*  ws    = (char*)d_ws;
  f16*   Areg  = (f16*)ws;
  size_t offH  = (size_t)Ntok * K2 * sizeof(f16);
  float* h1    = (float*)(ws + offH);
  size_t offW1 = offH + (size_t)Ntok * D1 * sizeof(float);
  f16*   Wt1   = (f16*)(ws + offW1);
  size_t offW2 = offW1 + (size_t)D1 * K1 * sizeof(f16);
  f16*   Wt2   = (f16*)(ws + offW2);

  prep_w_kernel<<<(D0 * D1 + 255) / 256, 256, 0, stream>>>(coef1, ssp1, sb1, Wt1, D0, D1);
  prep_w_kernel<<<(D1 * D2 + 255) / 256, 256, 0, stream>>>(coef2, ssp2, sb2, Wt2, D1, D2);

  basis_kernel<<<(Ntok * D0) / 256, 256, 0, stream>>>(x, Areg, Ntok * D0);

  gemm_f16<128><<<dim3(D1 / 128, Ntok / 128), 256, 0, stream>>>(Areg, Wt1, h1, ns1, nb1, D1, K1);

  basis_kernel<<<(Ntok * D1) / 256, 256, 0, stream>>>(h1, Areg, Ntok * D1);

  gemm_f16<64><<<dim3(D2 / 128, Ntok / 64), 256, 0, stream>>>(Areg, Wt2, out, ns2, nb2, D2, K2);

  ln_gelu_kernel<<<Ntok / 4, 256, 0, stream>>>(out, x, lgam, lbet, out, Ntok);
}

// Round 2
// 196.668 us; speedup vs baseline: 1.0684x; 1.0684x over previous
//
#include <hip/hip_runtime.h>
#include <cstdint>
#include <cstddef>

using f16   = _Float16;
using half8 = __attribute__((ext_vector_type(8))) _Float16;
using f32x4 = __attribute__((ext_vector_type(4))) float;

#define DINL __device__ __forceinline__

// global -> LDS async, 16B per lane. LDS dest must be wave-uniform base + lane*16.
DINL void gload_lds16(const void* gptr, void* lptr) {
  __builtin_amdgcn_global_load_lds(
      reinterpret_cast<const __attribute__((address_space(1))) uint32_t*>(
          reinterpret_cast<uintptr_t>(gptr)),
      reinterpret_cast<__attribute__((address_space(3))) uint32_t*>(
          reinterpret_cast<uintptr_t>(lptr)),
      16, 0, 0);
}

// x -> 8 fp16 channels: [B0..B5 uniform cubic B-spline, silu(x), 0].
// Closed-form uniform-knot evaluation, validated in round 1 (absmax 0.031).
DINL half8 expand8(float x) {
  float xs = (x + 3.0f) * 1.5f;       // (x - t0)/h, t0=-3, h=2/3
  float mf = floorf(xs);
  int   m  = (int)mf;
  float p0 = 0.f, p1 = 0.f, p2 = 0.f, p3 = 0.f;
  if (m >= 0 && m <= 8) {
    float u = xs - mf, u2 = u * u, u3 = u2 * u, um = 1.0f - u;
    p3 = u3 * (1.0f / 6.0f);
    p2 = (1.0f + 3.0f * u + 3.0f * u2 - 3.0f * u3) * (1.0f / 6.0f);
    p1 = (4.0f - 6.0f * u2 + 3.0f * u3) * (1.0f / 6.0f);
    p0 = um * um * um * (1.0f / 6.0f);
  }
  half8 o;
#pragma unroll
  for (int j = 0; j < 6; ++j) {
    int dmj = m - j;
    float v = (dmj == 0) ? p3 : (dmj == 1) ? p2 : (dmj == 2) ? p1
            : (dmj == 3) ? p0 : 0.0f;
    o[j] = (f16)v;
  }
  o[6] = (f16)(x / (1.0f + __expf(-x)));
  o[7] = (f16)0.0f;
  return o;
}

// ---------------------------------------------------------------------------
// Weight prep, PRE-SWIZZLED layout (rule 21): within each 8-dim chunk, the
// dim slot is stored at (d&7)^(n&7) so a LINEAR global_load_lds produces the
// swizzled LDS tile; the GEMM's ds_read applies the same XOR.
// ---------------------------------------------------------------------------
__global__ __launch_bounds__(256)
void prep_w_kernel(const float* __restrict__ coef, const float* __restrict__ ssp,
                   const float* __restrict__ sb, f16* __restrict__ Wt,
                   int Din, int Dout) {
  int idx = blockIdx.x * 256 + threadIdx.x;
  if (idx >= Din * Dout) return;
  int n = idx / Din;
  int d = idx - n * Din;
  float s = ssp[(size_t)d * Dout + n];
  const float* c = coef + ((size_t)d * Dout + n) * 6;
  half8 wv;
#pragma unroll
  for (int b = 0; b < 6; ++b) wv[b] = (f16)(c[b] * s);
  wv[6] = (f16)sb[(size_t)d * Dout + n];
  wv[7] = (f16)0.0f;
  int dp = (d & ~7) | ((d & 7) ^ (n & 7));   // inverse-swizzle source
  *reinterpret_cast<half8*>(Wt + ((size_t)n * Din + dp) * 8) = wv;
}

// ---------------------------------------------------------------------------
// Fused KAN layer: C[M,N] = expand(X)[M, 8*Dsrc] x Wt[N, 8*Dsrc]^T
// epilogue: ns[col]*acc + nb[col] -> Out   (FUSE_LN: + residual, LN, GELU)
// Block: BM=64 rows x BN=256 cols, 8 waves (2x4), BK=64 (8 dims), double-buf,
// ONE barrier per K-step. A reg-staged (issue-early global load, expand+ds_write
// late); B via global_load_lds from pre-swizzled Wt. XOR swizzle slot^(row&7).
// ---------------------------------------------------------------------------
template <bool FUSE_LN>
__global__ __launch_bounds__(512, 4)
void kan_gemm(const float* __restrict__ Xsrc, int Dsrc,
              const f16* __restrict__ Wt,
              const float* __restrict__ nscale, const float* __restrict__ nbias,
              int ldOut, float* __restrict__ Out,
              const float* __restrict__ resid,
              const float* __restrict__ gamma, const float* __restrict__ beta) {
  extern __shared__ char smem[];               // 81920 bytes at launch
  f16* bufA0 = (f16*)smem;                     //  8 KB
  f16* bufA1 = (f16*)(smem + 8192);            //  8 KB
  f16* bufB0 = (f16*)(smem + 16384);           // 32 KB
  f16* bufB1 = (f16*)(smem + 16384 + 32768);   // 32 KB

  const int tid  = threadIdx.x;
  const int w    = tid >> 6;
  const int lane = tid & 63;
  const int l15  = lane & 15, l7 = lane & 7, hi = lane >> 4;
  const int wm   = w >> 2, wn = w & 3;         // wave grid 2 x 4
  const int m0   = blockIdx.y * 64;
  const int n0   = blockIdx.x * 256;
  const int K    = Dsrc * 8;

  // A staging: one element per thread per K-step.
  const int arow = tid >> 3, adl = tid & 7;
  const float* asrc = Xsrc + (size_t)(m0 + arow) * Dsrc + adl;
  const int aoff = arow * 64 + 8 * (adl ^ (arow & 7));   // swizzled slot

  f32x4 acc[2][4] = {};

  auto stageB = [&](f16* buf, int k0) {
#pragma unroll
    for (int q = 0; q < 4; ++q) {
      int chunk = tid + q * 512;               // 2048 x 16B chunks
      int brow = chunk >> 3, boff = chunk & 7;
      gload_lds16(Wt + (size_t)(n0 + brow) * K + k0 + boff * 8, buf + chunk * 8);
    }
  };

  auto compute = [&](const f16* bA, const f16* bB) {
#pragma unroll
    for (int kk = 0; kk < 2; ++kk) {
      const int slot = kk * 4 + hi;
      half8 av[2], bv[4];
#pragma unroll
      for (int i = 0; i < 2; ++i)
        av[i] = *reinterpret_cast<const half8*>(
            bA + (wm * 32 + i * 16 + l15) * 64 + 8 * (slot ^ l7));
#pragma unroll
      for (int j = 0; j < 4; ++j)
        bv[j] = *reinterpret_cast<const half8*>(
            bB + (wn * 64 + j * 16 + l15) * 64 + 8 * (slot ^ l7));
#pragma unroll
      for (int i = 0; i < 2; ++i)
#pragma unroll
        for (int j = 0; j < 4; ++j)
          acc[i][j] = __builtin_amdgcn_mfma_f32_16x16x32_f16(av[i], bv[j], acc[i][j], 0, 0, 0);
    }
  };

  const int nsteps = Dsrc / 8;
  {
    float xv = asrc[0];
    stageB(bufB0, 0);
    *reinterpret_cast<half8*>(bufA0 + aoff) = expand8(xv);
  }
  __syncthreads();

  for (int s = 0; s < nsteps; ++s) {
    const bool odd = s & 1;
    f16* curA = odd ? bufA1 : bufA0;
    f16* curB = odd ? bufB1 : bufB0;
    f16* nxtA = odd ? bufA0 : bufA1;
    f16* nxtB = odd ? bufB0 : bufB1;
    float xv = 0.f;
    const bool hasnext = (s + 1 < nsteps);
    if (hasnext) {
      xv = asrc[(s + 1) * 8];                  // issue early (T14)
      stageB(nxtB, (s + 1) * 64);              // async into other buffer
    }
    compute(curA, curB);                       // MFMA hides the loads
    if (hasnext)
      *reinterpret_cast<half8*>(nxtA + aoff) = expand8(xv);  // write late
    __syncthreads();                           // single barrier per step
  }

  if (!FUSE_LN) {
#pragma unroll
    for (int j = 0; j < 4; ++j) {
      int col = n0 + wn * 64 + j * 16 + l15;
      float ns = nscale[col], nb = nbias[col];
#pragma unroll
      for (int i = 0; i < 2; ++i)
#pragma unroll
        for (int r = 0; r < 4; ++r) {
          int row = m0 + wm * 32 + i * 16 + hi * 4 + r;
          Out[(size_t)row * ldOut + col] = ns * acc[i][j][r] + nb;
        }
    }
  } else {
    // reuse LDS (loop ended with a barrier; no pending reads) as [64][260] f32
    float* lnbuf = (float*)smem;
#pragma unroll
    for (int j = 0; j < 4; ++j) {
      int lcol = wn * 64 + j * 16 + l15;
      float ns = nscale[lcol], nb = nbias[lcol];
#pragma unroll
      for (int i = 0; i < 2; ++i)
#pragma unroll
        for (int r = 0; r < 4; ++r) {
          int row = wm * 32 + i * 16 + hi * 4 + r;
          lnbuf[row * 260 + lcol] = ns * acc[i][j][r] + nb;
        }
    }
    __syncthreads();
    float g[4], b4[4];
#pragma unroll
    for (int c = 0; c < 4; ++c) {
      g[c]  = gamma[lane * 4 + c];
      b4[c] = beta[lane * 4 + c];
    }
#pragma unroll
    for (int rr = 0; rr < 8; ++rr) {
      int row = w * 8 + rr;
      const float4 hv = *reinterpret_cast<const float4*>(&lnbuf[row * 260 + lane * 4]);
      const float4 xr = *reinterpret_cast<const float4*>(&resid[(size_t)(m0 + row) * 256 + lane * 4]);
      float v[4] = {hv.x + xr.x, hv.y + xr.y, hv.z + xr.z, hv.w + xr.w};
      float s = v[0] + v[1] + v[2] + v[3];
#pragma unroll
      for (int o = 32; o >= 1; o >>= 1) s += __shfl_xor(s, o);
      float mu = s * (1.0f / 256.0f);
      float vs = 0.f;
#pragma unroll
      for (int c = 0; c < 4; ++c) { float d = v[c] - mu; vs += d * d; }
#pragma unroll
      for (int o = 32; o >= 1; o >>= 1) vs += __shfl_xor(vs, o);
      float inv = rsqrtf(vs * (1.0f / 256.0f) + 1e-5f);
      float o4[4];
#pragma unroll
      for (int c = 0; c < 4; ++c) {
        float t = (v[c] - mu) * inv * g[c] + b4[c];
        o4[c] = 0.5f * t * (1.0f + erff(t * 0.70710678118654752f));
      }
      *reinterpret_cast<float4*>(&Out[(size_t)(m0 + row) * 256 + lane * 4]) =
          make_float4(o4[0], o4[1], o4[2], o4[3]);
    }
  }
}

// ---------------------------------------------------------------------------
extern "C" void kernel_launch(void* const* d_in, const int* in_sizes, int n_in,
                              void* d_out, int out_size, void* d_ws, size_t ws_size,
                              hipStream_t stream) {
  (void)in_sizes; (void)n_in; (void)out_size; (void)ws_size;
  const float* x     = (const float*)d_in[0];
  const float* coef1 = (const float*)d_in[2];
  const float* sb1   = (const float*)d_in[3];
  const float* ssp1  = (const float*)d_in[4];
  const float* ns1   = (const float*)d_in[5];
  const float* nb1   = (const float*)d_in[6];
  const float* coef2 = (const float*)d_in[8];
  const float* sb2   = (const float*)d_in[9];
  const float* ssp2  = (const float*)d_in[10];
  const float* ns2   = (const float*)d_in[11];
  const float* nb2   = (const float*)d_in[12];
  const float* lgam  = (const float*)d_in[13];
  const float* lbet  = (const float*)d_in[14];
  float* out = (float*)d_out;

  const int Ntok = 16 * 1024;
  const int D0 = 256, D1 = 512, D2 = 256;

  // ws: h1 [Ntok,512] f32 (33.5MB) | Wt1 2MB | Wt2 2MB
  char*  ws  = (char*)d_ws;
  float* h1  = (float*)ws;
  f16*   Wt1 = (f16*)(ws + (size_t)Ntok * D1 * sizeof(float));
  f16*   Wt2 = (f16*)(ws + (size_t)Ntok * D1 * sizeof(float) + (size_t)D1 * D0 * 8 * sizeof(f16));

  prep_w_kernel<<<(D0 * D1 + 255) / 256, 256, 0, stream>>>(coef1, ssp1, sb1, Wt1, D0, D1);
  prep_w_kernel<<<(D1 * D2 + 255) / 256, 256, 0, stream>>>(coef2, ssp2, sb2, Wt2, D1, D2);

  // layer 1: [16384 x 2048] x [512 x 2048]^T -> h1 (fp32)
  kan_gemm<false><<<dim3(D1 / 256, Ntok / 64), 512, 81920, stream>>>(
      x, D0, Wt1, ns1, nb1, D1, h1, nullptr, nullptr, nullptr);

  // layer 2 + residual + LN + GELU: [16384 x 4096] x [256 x 4096]^T -> out
  kan_gemm<true><<<dim3(D2 / 256, Ntok / 64), 512, 81920, stream>>>(
      h1, D1, Wt2, ns2, nb2, D2, out, x, lgam, lbet);
}